// Round 2
// baseline (4519.507 us; speedup 1.0000x reference)
//
#include <hip/hip_runtime.h>
#include <hip/hip_bf16.h>

typedef __hip_bfloat16 bf16;
typedef __attribute__((ext_vector_type(8))) short short8;
typedef __attribute__((ext_vector_type(4))) short short4v;
typedef __attribute__((ext_vector_type(4))) float f32x4;

#define Bz   256
#define Hz   512
#define Tz   168
#define OUTz 24
#define Fz   8

__device__ __forceinline__ float sigm(float x) { return 1.0f / (1.0f + __expf(-x)); }

__device__ __forceinline__ short f2bf(float f) {
    union { float f; unsigned int u; } v; v.f = f;
    unsigned int r = v.u + 0x7fffu + ((v.u >> 16) & 1u);   // RNE
    return (short)(r >> 16);
}

// ---------------- weight fp32 -> bf16 conversion (once per call) -------------
struct CvtEntry { const float* s; bf16* d; int n; };
struct CvtArgs  { CvtEntry e[7]; };

__global__ __launch_bounds__(256) void convert_kernel(CvtArgs a)
{
    CvtEntry en = a.e[blockIdx.y];
    int n4 = en.n >> 2;
    const float4* s4 = (const float4*)en.s;
    short4v* d4 = (short4v*)en.d;
    for (int i = blockIdx.x * blockDim.x + threadIdx.x; i < n4;
         i += gridDim.x * blockDim.x) {
        float4 f = s4[i];
        short4v o;
        o[0] = f2bf(f.x); o[1] = f2bf(f.y); o[2] = f2bf(f.z); o[3] = f2bf(f.w);
        d4[i] = o;
    }
}

// zero h ping-pong + c buffers (first 2MB of ws)
__global__ void init_kernel(unsigned int* ws)
{
    const int total = 2097152 / 4;
    for (int i = blockIdx.x * blockDim.x + threadIdx.x; i < total;
         i += gridDim.x * blockDim.x)
        ws[i] = 0u;
}

// ---------------- one LSTM cell step, all 256 batch rows ---------------------
// Block = 256 threads (4 waves); block computes a 32(m) x 16(j) tile of h/c.
// Wave w computes gate group w (i,f,g,o) via 16x16x32 bf16 MFMA.
// grid = dim3(32, 8): blockIdx.x -> j-tile, blockIdx.y -> m-tile.
template<int IN_DIM>
__global__ __launch_bounds__(256)
void lstm_step(const float* __restrict__ xf,      // [B][*] fp32 (IN_DIM==F)
               const bf16* __restrict__ xh,       // [B][H] bf16 (IN_DIM==H)
               int xs,                            // x row stride (elements)
               const bf16* __restrict__ h_in,     // [B][H]
               bf16* __restrict__ h_out,          // [B][H]
               float* __restrict__ c,             // [B][H] in/out fp32
               const float* __restrict__ Wih_f,   // [4H][F] fp32 (IN_DIM==F)
               const bf16* __restrict__ Wih_b,    // [4H][H] bf16 (IN_DIM==H)
               const bf16* __restrict__ Whh_b,    // [4H][H] bf16
               const float* __restrict__ bih,     // [4H] fp32
               const float* __restrict__ bhh)     // [4H] fp32
{
    __shared__ float gl[4][32][16];
    const int tid = threadIdx.x;
    const int w   = tid >> 6;      // gate group 0..3 (i,f,g,o)
    const int l   = tid & 63;
    const int lr  = l & 15;        // A row / B col / C col
    const int lg  = l >> 4;        // k-group
    const int m0  = blockIdx.y * 32;
    const int j0  = blockIdx.x * 16;
    const int n   = w * Hz + j0 + lr;   // gate row (row of Wih/Whh)

    f32x4 acc0 = {0.f, 0.f, 0.f, 0.f};
    f32x4 acc1 = {0.f, 0.f, 0.f, 0.f};

    // h_prev @ Whh^T
    {
        const bf16* wrow = Whh_b + (size_t)n * Hz + 8 * lg;
        const bf16* ar0  = h_in + (size_t)(m0 + lr) * Hz + 8 * lg;
        const bf16* ar1  = h_in + (size_t)(m0 + 16 + lr) * Hz + 8 * lg;
        #pragma unroll
        for (int kc = 0; kc < Hz; kc += 32) {
            short8 bfrag = *(const short8*)(wrow + kc);
            short8 a0    = *(const short8*)(ar0 + kc);
            short8 a1    = *(const short8*)(ar1 + kc);
            acc0 = __builtin_amdgcn_mfma_f32_16x16x32_bf16(a0, bfrag, acc0, 0, 0, 0);
            acc1 = __builtin_amdgcn_mfma_f32_16x16x32_bf16(a1, bfrag, acc1, 0, 0, 0);
        }
    }
    // x @ Wih^T, H-wide input (layer 1)
    if (IN_DIM == Hz) {
        const bf16* wrow = Wih_b + (size_t)n * Hz + 8 * lg;
        const bf16* ar0  = xh + (size_t)(m0 + lr) * xs + 8 * lg;
        const bf16* ar1  = xh + (size_t)(m0 + 16 + lr) * xs + 8 * lg;
        #pragma unroll
        for (int kc = 0; kc < Hz; kc += 32) {
            short8 bfrag = *(const short8*)(wrow + kc);
            short8 a0    = *(const short8*)(ar0 + kc);
            short8 a1    = *(const short8*)(ar1 + kc);
            acc0 = __builtin_amdgcn_mfma_f32_16x16x32_bf16(a0, bfrag, acc0, 0, 0, 0);
            acc1 = __builtin_amdgcn_mfma_f32_16x16x32_bf16(a1, bfrag, acc1, 0, 0, 0);
        }
    }

    float bias = bih[n] + bhh[n];

    // x @ Wih^T, tiny input (F=8): exact fp32 scalar path
    if (IN_DIM == Fz) {
        const float* wr = Wih_f + (size_t)n * Fz;
        float4 wa = *(const float4*)wr;
        float4 wb = *(const float4*)(wr + 4);
        #pragma unroll
        for (int s = 0; s < 2; ++s) {
            #pragma unroll
            for (int r = 0; r < 4; ++r) {
                int m = m0 + s * 16 + lg * 4 + r;
                const float* xr = xf + (size_t)m * xs;
                float4 xa = *(const float4*)xr;
                float4 xb = *(const float4*)(xr + 4);
                float sum = wa.x * xa.x + wa.y * xa.y + wa.z * xa.z + wa.w * xa.w
                          + wb.x * xb.x + wb.y * xb.y + wb.z * xb.z + wb.w * xb.w;
                if (s == 0) acc0[r] += sum; else acc1[r] += sum;
            }
        }
    }

    // C layout (m89-verified): col = lane&15, row = (lane>>4)*4 + reg
    #pragma unroll
    for (int r = 0; r < 4; ++r) {
        gl[w][lg * 4 + r][lr]      = acc0[r] + bias;
        gl[w][16 + lg * 4 + r][lr] = acc1[r] + bias;
    }
    __syncthreads();

    // activation + state update: 512 (m,j) elements over 256 threads
    #pragma unroll
    for (int p = 0; p < 2; ++p) {
        int idx = tid + p * 256;
        int ml = idx >> 4, jl = idx & 15;
        float gi = gl[0][ml][jl];
        float gf = gl[1][ml][jl];
        float gg = gl[2][ml][jl];
        float go = gl[3][ml][jl];
        size_t off = (size_t)(m0 + ml) * Hz + j0 + jl;
        float cv = sigm(gf) * c[off] + sigm(gi) * tanhf(gg);
        float hv = sigm(go) * tanhf(cv);
        c[off] = cv;
        h_out[off] = __float2bfloat16(hv);
    }
}

// pred = h1 @ fcW^T + fcb ; fp32 out slice (row stride OUT*F)
__global__ __launch_bounds__(256)
void fc_kernel(const bf16* __restrict__ h, const bf16* __restrict__ W,
               const float* __restrict__ b, float* __restrict__ out)
{
    int g = blockIdx.x * 256 + threadIdx.x;   // 0..2047
    int m = g >> 3, f = g & 7;
    const short8* hr = (const short8*)(h + (size_t)m * Hz);
    const short8* wr = (const short8*)(W + (size_t)f * Hz);
    float s = b[f];
    #pragma unroll 4
    for (int k = 0; k < Hz / 8; ++k) {
        short8 hv = hr[k];
        short8 wv = wr[k];
        #pragma unroll
        for (int i = 0; i < 8; ++i) {
            union { unsigned int u; float f; } a, bb;
            a.u  = ((unsigned int)(unsigned short)hv[i]) << 16;
            bb.u = ((unsigned int)(unsigned short)wv[i]) << 16;
            s += a.f * bb.f;
        }
    }
    out[(size_t)m * (OUTz * Fz) + f] = s;
}

extern "C" void kernel_launch(void* const* d_in, const int* in_sizes, int n_in,
                              void* d_out, int out_size, void* d_ws, size_t ws_size,
                              hipStream_t stream)
{
    (void)in_sizes; (void)n_in; (void)out_size; (void)ws_size;
    const float* src   = (const float*)d_in[0];
    const float* eWih0 = (const float*)d_in[1];
    const float* eWhh0 = (const float*)d_in[2];
    const float* ebih0 = (const float*)d_in[3];
    const float* ebhh0 = (const float*)d_in[4];
    const float* eWih1 = (const float*)d_in[5];
    const float* eWhh1 = (const float*)d_in[6];
    const float* ebih1 = (const float*)d_in[7];
    const float* ebhh1 = (const float*)d_in[8];
    const float* dWih0 = (const float*)d_in[9];
    const float* dWhh0 = (const float*)d_in[10];
    const float* dbih0 = (const float*)d_in[11];
    const float* dbhh0 = (const float*)d_in[12];
    const float* dWih1 = (const float*)d_in[13];
    const float* dWhh1 = (const float*)d_in[14];
    const float* dbih1 = (const float*)d_in[15];
    const float* dbhh1 = (const float*)d_in[16];
    const float* fcW   = (const float*)d_in[17];
    const float* fcb   = (const float*)d_in[18];

    float* out = (float*)d_out;
    char*  ws  = (char*)d_ws;
    bf16*  h0[2] = { (bf16*)(ws + 0),      (bf16*)(ws + 262144) };
    bf16*  h1[2] = { (bf16*)(ws + 524288), (bf16*)(ws + 786432) };
    float* c0 = (float*)(ws + 1048576);
    float* c1 = (float*)(ws + 1572864);

    const int NH = 2048 * 512;   // big weight element count
    bf16* eWhh0_b = (bf16*)(ws + 2097152);
    bf16* eWih1_b = (bf16*)(ws + 4194304);
    bf16* eWhh1_b = (bf16*)(ws + 6291456);
    bf16* dWhh0_b = (bf16*)(ws + 8388608);
    bf16* dWih1_b = (bf16*)(ws + 10485760);
    bf16* dWhh1_b = (bf16*)(ws + 12582912);
    bf16* fcW_b   = (bf16*)(ws + 14680064);

    CvtArgs ca;
    ca.e[0] = { eWhh0, eWhh0_b, NH };
    ca.e[1] = { eWih1, eWih1_b, NH };
    ca.e[2] = { eWhh1, eWhh1_b, NH };
    ca.e[3] = { dWhh0, dWhh0_b, NH };
    ca.e[4] = { dWih1, dWih1_b, NH };
    ca.e[5] = { dWhh1, dWhh1_b, NH };
    ca.e[6] = { fcW,   fcW_b,   Fz * Hz };
    convert_kernel<<<dim3(128, 7), dim3(256), 0, stream>>>(ca);
    init_kernel<<<dim3(512), dim3(256), 0, stream>>>((unsigned int*)ws);

    dim3 grid(32, 8), blk(256);

    // encoder
    for (int t = 0; t < Tz; ++t) {
        int p = t & 1;
        lstm_step<Fz><<<grid, blk, 0, stream>>>(src + t * Fz, nullptr, Tz * Fz,
                                                h0[p], h0[1 - p], c0,
                                                eWih0, nullptr, eWhh0_b, ebih0, ebhh0);
        lstm_step<Hz><<<grid, blk, 0, stream>>>(nullptr, h0[1 - p], Hz,
                                                h1[p], h1[1 - p], c1,
                                                nullptr, eWih1_b, eWhh1_b, ebih1, ebhh1);
    }
    // decoder (encoder ends with state in buffer 0 for both layers)
    for (int s = 0; s < OUTz; ++s) {
        int p = s & 1;
        const float* x;
        int xs;
        if (s == 0) { x = src + (Tz - 1) * Fz; xs = Tz * Fz; }
        else        { x = out + (s - 1) * Fz;  xs = OUTz * Fz; }
        lstm_step<Fz><<<grid, blk, 0, stream>>>(x, nullptr, xs,
                                                h0[p], h0[1 - p], c0,
                                                dWih0, nullptr, dWhh0_b, dbih0, dbhh0);
        lstm_step<Hz><<<grid, blk, 0, stream>>>(nullptr, h0[1 - p], Hz,
                                                h1[p], h1[1 - p], c1,
                                                nullptr, dWih1_b, dWhh1_b, dbih1, dbhh1);
        fc_kernel<<<dim3(8), blk, 0, stream>>>(h1[1 - p], fcW_b, fcb, out + s * Fz);
    }
}